// Round 1
// baseline (920.685 us; speedup 1.0000x reference)
//
#include <hip/hip_runtime.h>

#define N_NODES 100000
#define N_EDGES 1600000
#define IN_DIM 512
#define HID 64
#define NCLS 16
#define NB ((N_NODES + 1023) / 1024)   // scan blocks (98)

// ---------- graph preprocessing ----------

__global__ void k_init(float* deg, int* cntA, int* cnt2) {
    int i = blockIdx.x * 256 + threadIdx.x;
    if (i < N_NODES) { deg[i] = 1.0f; cntA[i] = 0; cnt2[i] = 0; }
}

__global__ void k_deg(const int* __restrict__ src, const int* __restrict__ dst,
                      const float* __restrict__ w, float* deg, int* cntA) {
    int e = blockIdx.x * 256 + threadIdx.x;
    if (e < N_EDGES) {
        int d = dst[e];
        atomicAdd(&deg[d], w[e]);
        atomicAdd(&cntA[d], 1);
    }
}

__global__ void k_rsqrt(float* deg) {
    int i = blockIdx.x * 256 + threadIdx.x;
    if (i < N_NODES) deg[i] = rsqrtf(deg[i]);   // deg >= 1 (self loop), so no guard needed
}

// exclusive scan of cntA -> ptr, 1024 elems/block
__global__ void k_scan1(const int* __restrict__ cntA, int* ptr, int* bsum) {
    __shared__ int s[256];
    int t = threadIdx.x;
    int i0 = blockIdx.x * 1024 + t * 4;
    int c[4];
#pragma unroll
    for (int j = 0; j < 4; j++) c[j] = (i0 + j < N_NODES) ? cntA[i0 + j] : 0;
    int sum4 = c[0] + c[1] + c[2] + c[3];
    s[t] = sum4;
    __syncthreads();
    int v = sum4;
    for (int off = 1; off < 256; off <<= 1) {
        int add = (t >= off) ? s[t - off] : 0;
        __syncthreads();
        v += add;
        s[t] = v;
        __syncthreads();
    }
    int run = v - sum4;  // exclusive prefix of this thread's chunk
#pragma unroll
    for (int j = 0; j < 4; j++) {
        if (i0 + j < N_NODES) ptr[i0 + j] = run;
        run += c[j];
    }
    if (t == 255) bsum[blockIdx.x] = v;  // block total
}

__global__ void k_scan2(int* bsum, int* ptr) {
    __shared__ int s[128];
    int t = threadIdx.x;
    int val = (t < NB) ? bsum[t] : 0;
    s[t] = val;
    __syncthreads();
    int v = val;
    for (int off = 1; off < 128; off <<= 1) {
        int add = (t >= off) ? s[t - off] : 0;
        __syncthreads();
        v += add;
        s[t] = v;
        __syncthreads();
    }
    if (t < NB) bsum[t] = v - val;  // exclusive block offsets
    if (t == 0) ptr[N_NODES] = N_EDGES;
}

__global__ void k_scan3(int* ptr, const int* __restrict__ bsum) {
    int t = threadIdx.x;
    int i0 = blockIdx.x * 1024 + t * 4;
    int add = bsum[blockIdx.x];
#pragma unroll
    for (int j = 0; j < 4; j++)
        if (i0 + j < N_NODES) ptr[i0 + j] += add;
}

__global__ void k_scatter(const int* __restrict__ src, const int* __restrict__ dst,
                          const float* __restrict__ w, const float* __restrict__ dis,
                          const int* __restrict__ ptr, int* cnt2,
                          int* csr_src, float* csr_w) {
    int e = blockIdx.x * 256 + threadIdx.x;
    if (e < N_EDGES) {
        int sN = src[e], d = dst[e];
        int p = ptr[d] + atomicAdd(&cnt2[d], 1);
        csr_src[p] = sN;
        csr_w[p] = dis[sN] * w[e] * dis[d];
    }
}

// ---------- layer 1 GEMM: h1 = x @ W1  (f32 vector) ----------
// 64 rows/block, 4 waves, each wave: 16 rows x 64 cols (lane = col)

__global__ __launch_bounds__(256) void k_gemm1(const float* __restrict__ x,
                                               const float* __restrict__ W1,
                                               float* __restrict__ h1) {
    __shared__ float xs[64][32];
    __shared__ float ws[32][64];
    int row0 = blockIdx.x * 64;
    int wave = threadIdx.x >> 6, lane = threadIdx.x & 63;
    int li = threadIdx.x >> 3;          // 0..31
    int lj = (threadIdx.x & 7) << 2;    // 0,4,..,28

    float acc[16];
#pragma unroll
    for (int r = 0; r < 16; r++) acc[r] = 0.f;

    for (int k0 = 0; k0 < IN_DIM; k0 += 32) {
        __syncthreads();
#pragma unroll
        for (int h = 0; h < 2; h++) {
            int r = li + 32 * h;
            int gr = row0 + r;
            if (gr >= N_NODES) gr = N_NODES - 1;
            *(float4*)&xs[r][lj] = *(const float4*)(x + (size_t)gr * IN_DIM + k0 + lj);
        }
        {
            int kk = li, c = (threadIdx.x & 7) << 3;
            const float* wp = W1 + (size_t)(k0 + kk) * HID + c;
            *(float4*)&ws[kk][c]     = *(const float4*)(wp);
            *(float4*)&ws[kk][c + 4] = *(const float4*)(wp + 4);
        }
        __syncthreads();
#pragma unroll
        for (int kk4 = 0; kk4 < 8; kk4++) {
            float w0 = ws[kk4 * 4 + 0][lane];
            float w1 = ws[kk4 * 4 + 1][lane];
            float w2 = ws[kk4 * 4 + 2][lane];
            float w3 = ws[kk4 * 4 + 3][lane];
#pragma unroll
            for (int r = 0; r < 16; r++) {
                float4 xv = *(const float4*)&xs[wave * 16 + r][kk4 * 4];
                acc[r] = fmaf(xv.x, w0, acc[r]);
                acc[r] = fmaf(xv.y, w1, acc[r]);
                acc[r] = fmaf(xv.z, w2, acc[r]);
                acc[r] = fmaf(xv.w, w3, acc[r]);
            }
        }
    }
#pragma unroll
    for (int r = 0; r < 16; r++) {
        int gr = row0 + wave * 16 + r;
        if (gr < N_NODES) h1[(size_t)gr * HID + lane] = acc[r];
    }
}

// ---------- layer 1 aggregation + bias + relu (wave per node, lane = dim) ----------

__global__ __launch_bounds__(256) void k_agg1(const float* __restrict__ h1,
                                              const int* __restrict__ ptr,
                                              const int* __restrict__ csr_src,
                                              const float* __restrict__ csr_w,
                                              const float* __restrict__ dis,
                                              const float* __restrict__ b1,
                                              float* __restrict__ a1) {
    int wave = threadIdx.x >> 6, lane = threadIdx.x & 63;
    int v = blockIdx.x * 4 + wave;
    if (v >= N_NODES) return;
    float dv = dis[v];
    float acc = h1[(size_t)v * HID + lane] * dv * dv;   // self loop
    int p0 = ptr[v], p1 = ptr[v + 1];
    for (int p = p0; p < p1; p++)
        acc += csr_w[p] * h1[(size_t)csr_src[p] * HID + lane];
    float r = acc + b1[lane];
    a1[(size_t)v * HID + lane] = r > 0.f ? r : 0.f;
}

// ---------- layer 2 GEMM: h2 = a1 @ W2 ----------

__global__ __launch_bounds__(256) void k_gemm2(const float* __restrict__ a1,
                                               const float* __restrict__ W2,
                                               float* __restrict__ h2) {
    __shared__ float ws[HID * NCLS];
    for (int i = threadIdx.x; i < HID * NCLS; i += 256) ws[i] = W2[i];
    __syncthreads();
    int t = blockIdx.x * 256 + threadIdx.x;
    int v = t >> 4, c = t & 15;
    if (v >= N_NODES) return;
    const float* row = a1 + (size_t)v * HID;
    float acc = 0.f;
#pragma unroll
    for (int k = 0; k < HID; k += 4) {
        float4 av = *(const float4*)(row + k);
        acc = fmaf(av.x, ws[(k + 0) * NCLS + c], acc);
        acc = fmaf(av.y, ws[(k + 1) * NCLS + c], acc);
        acc = fmaf(av.z, ws[(k + 2) * NCLS + c], acc);
        acc = fmaf(av.w, ws[(k + 3) * NCLS + c], acc);
    }
    h2[(size_t)v * NCLS + c] = acc;
}

// ---------- layer 2 aggregation + bias + log_softmax (16 lanes per node) ----------

__global__ __launch_bounds__(256) void k_agg2(const float* __restrict__ h2,
                                              const int* __restrict__ ptr,
                                              const int* __restrict__ csr_src,
                                              const float* __restrict__ csr_w,
                                              const float* __restrict__ dis,
                                              const float* __restrict__ b2,
                                              float* __restrict__ out) {
    int t = blockIdx.x * 256 + threadIdx.x;
    int v = t >> 4, c = t & 15;
    if (v >= N_NODES) return;
    float dv = dis[v];
    float acc = h2[(size_t)v * NCLS + c] * dv * dv;
    int p0 = ptr[v], p1 = ptr[v + 1];
    for (int p = p0; p < p1; p++)
        acc += csr_w[p] * h2[(size_t)csr_src[p] * NCLS + c];
    acc += b2[c];
    // log-softmax over the 16-lane group
    float m = acc;
#pragma unroll
    for (int off = 8; off >= 1; off >>= 1) m = fmaxf(m, __shfl_xor(m, off, 16));
    float e = expf(acc - m);
    float s = e;
#pragma unroll
    for (int off = 8; off >= 1; off >>= 1) s += __shfl_xor(s, off, 16);
    out[(size_t)v * NCLS + c] = acc - m - logf(s);
}

// ---------- launch ----------

extern "C" void kernel_launch(void* const* d_in, const int* in_sizes, int n_in,
                              void* d_out, int out_size, void* d_ws, size_t ws_size,
                              hipStream_t stream) {
    const float* x  = (const float*)d_in[0];
    const int*   ei = (const int*)d_in[1];
    const float* w  = (const float*)d_in[2];
    const float* W1 = (const float*)d_in[3];
    const float* b1 = (const float*)d_in[4];
    const float* W2 = (const float*)d_in[5];
    const float* b2 = (const float*)d_in[6];
    const int* src = ei;               // edge_index[0]
    const int* dst = ei + N_EDGES;     // edge_index[1]

    char* wsb = (char*)d_ws;
    size_t off = 0;
    auto alloc = [&](size_t bytes) {
        void* p = wsb + off;
        off += (bytes + 255) & ~(size_t)255;
        return p;
    };
    float* deg   = (float*)alloc((size_t)N_NODES * 4);      // becomes dis after k_rsqrt
    int*   cntA  = (int*)  alloc((size_t)N_NODES * 4);
    int*   cnt2  = (int*)  alloc((size_t)N_NODES * 4);
    int*   ptr   = (int*)  alloc((size_t)(N_NODES + 1) * 4);
    int*   bsum  = (int*)  alloc((size_t)NB * 4);
    int*   csr_s = (int*)  alloc((size_t)N_EDGES * 4);
    float* csr_w = (float*)alloc((size_t)N_EDGES * 4);
    float* h1    = (float*)alloc((size_t)N_NODES * HID * 4);
    float* a1    = (float*)alloc((size_t)N_NODES * HID * 4);
    float* h2    = (float*)alloc((size_t)N_NODES * NCLS * 4);

    float* outp = (float*)d_out;

    k_init   <<<(N_NODES + 255) / 256, 256, 0, stream>>>(deg, cntA, cnt2);
    k_deg    <<<(N_EDGES + 255) / 256, 256, 0, stream>>>(src, dst, w, deg, cntA);
    k_rsqrt  <<<(N_NODES + 255) / 256, 256, 0, stream>>>(deg);
    k_scan1  <<<NB, 256, 0, stream>>>(cntA, ptr, bsum);
    k_scan2  <<<1, 128, 0, stream>>>(bsum, ptr);
    k_scan3  <<<NB, 256, 0, stream>>>(ptr, bsum);
    k_scatter<<<(N_EDGES + 255) / 256, 256, 0, stream>>>(src, dst, w, deg, ptr, cnt2, csr_s, csr_w);
    k_gemm1  <<<(N_NODES + 63) / 64, 256, 0, stream>>>(x, W1, h1);
    k_agg1   <<<(N_NODES + 3) / 4, 256, 0, stream>>>(h1, ptr, csr_s, csr_w, deg, b1, a1);
    k_gemm2  <<<(N_NODES * NCLS + 255) / 256, 256, 0, stream>>>(a1, W2, h2);
    k_agg2   <<<(N_NODES * NCLS + 255) / 256, 256, 0, stream>>>(h2, ptr, csr_s, csr_w, deg, b2, outp);
}

// Round 2
// 691.975 us; speedup vs baseline: 1.3305x; 1.3305x over previous
//
#include <hip/hip_runtime.h>
#include <hip/hip_bf16.h>

#define N_NODES 100000
#define N_EDGES 1600000
#define IN_DIM 512
#define HID 64
#define NCLS 16
#define NB ((N_NODES + 1023) / 1024)   // scan blocks (98)

typedef __attribute__((ext_vector_type(8))) short bf16x8;
typedef __attribute__((ext_vector_type(8))) unsigned short ushort8;
typedef __attribute__((ext_vector_type(4))) float f32x4;

static __device__ __forceinline__ unsigned short f2bf(float f) {
    // round-to-nearest-even f32 -> bf16 (values are finite/normal here)
    union { float f; unsigned int u; } v; v.f = f;
    unsigned int u = v.u;
    unsigned int r = (u + 0x7fffu + ((u >> 16) & 1u)) >> 16;
    return (unsigned short)r;
}

// ---------- graph preprocessing ----------

__global__ void k_init(float* deg, int* cntA, int* cnt2) {
    int i = blockIdx.x * 256 + threadIdx.x;
    if (i < N_NODES) { deg[i] = 1.0f; cntA[i] = 0; cnt2[i] = 0; }
}

__global__ void k_deg(const int* __restrict__ src, const int* __restrict__ dst,
                      const float* __restrict__ w, float* deg, int* cntA) {
    int e = blockIdx.x * 256 + threadIdx.x;
    if (e < N_EDGES) {
        int d = dst[e];
        atomicAdd(&deg[d], w[e]);
        atomicAdd(&cntA[d], 1);
    }
}

__global__ void k_rsqrt(float* deg) {
    int i = blockIdx.x * 256 + threadIdx.x;
    if (i < N_NODES) deg[i] = rsqrtf(deg[i]);   // deg >= 1 (self loop)
}

// exclusive scan of cntA -> ptr, 1024 elems/block
__global__ void k_scan1(const int* __restrict__ cntA, int* ptr, int* bsum) {
    __shared__ int s[256];
    int t = threadIdx.x;
    int i0 = blockIdx.x * 1024 + t * 4;
    int c[4];
#pragma unroll
    for (int j = 0; j < 4; j++) c[j] = (i0 + j < N_NODES) ? cntA[i0 + j] : 0;
    int sum4 = c[0] + c[1] + c[2] + c[3];
    s[t] = sum4;
    __syncthreads();
    int v = sum4;
    for (int off = 1; off < 256; off <<= 1) {
        int add = (t >= off) ? s[t - off] : 0;
        __syncthreads();
        v += add;
        s[t] = v;
        __syncthreads();
    }
    int run = v - sum4;
#pragma unroll
    for (int j = 0; j < 4; j++) {
        if (i0 + j < N_NODES) ptr[i0 + j] = run;
        run += c[j];
    }
    if (t == 255) bsum[blockIdx.x] = v;
}

__global__ void k_scan2(int* bsum, int* ptr) {
    __shared__ int s[128];
    int t = threadIdx.x;
    int val = (t < NB) ? bsum[t] : 0;
    s[t] = val;
    __syncthreads();
    int v = val;
    for (int off = 1; off < 128; off <<= 1) {
        int add = (t >= off) ? s[t - off] : 0;
        __syncthreads();
        v += add;
        s[t] = v;
        __syncthreads();
    }
    if (t < NB) bsum[t] = v - val;
    if (t == 0) ptr[N_NODES] = N_EDGES;
}

__global__ void k_scan3(int* ptr, const int* __restrict__ bsum) {
    int t = threadIdx.x;
    int i0 = blockIdx.x * 1024 + t * 4;
    int add = bsum[blockIdx.x];
#pragma unroll
    for (int j = 0; j < 4; j++)
        if (i0 + j < N_NODES) ptr[i0 + j] += add;
}

__global__ void k_scatter(const int* __restrict__ src, const int* __restrict__ dst,
                          const float* __restrict__ w, const float* __restrict__ dis,
                          const int* __restrict__ ptr, int* cnt2,
                          int* csr_src, float* csr_w) {
    int e = blockIdx.x * 256 + threadIdx.x;
    if (e < N_EDGES) {
        int sN = src[e], d = dst[e];
        int p = ptr[d] + atomicAdd(&cnt2[d], 1);
        csr_src[p] = sN;
        csr_w[p] = dis[sN] * w[e] * dis[d];
    }
}

// ---------- W1 transpose+cvt: wt[n][k] bf16, n=0..63, k=0..511 ----------

__global__ void k_prep_w1(const float* __restrict__ W1, unsigned short* __restrict__ wt) {
    int t = blockIdx.x * 256 + threadIdx.x;   // 32768 threads
    if (t < HID * IN_DIM) {
        int n = t >> 9, k = t & 511;
        wt[t] = f2bf(W1[(size_t)k * HID + n]);
    }
}

// ---------- layer 1 GEMM via bf16 MFMA: h1 = x @ W1 ----------
// block = 256 thr (4 waves) computes 64 rows x 64 cols; K staged 64 at a time.
// LDS padded to 72 bf16/row -> fragment reads are 2-way-conflict (free).

#define LDK 72

__global__ __launch_bounds__(256) void k_gemm1(const float* __restrict__ x,
                                               const unsigned short* __restrict__ wt,
                                               float* __restrict__ h1) {
    __shared__ unsigned short xs[64][LDK];
    __shared__ unsigned short ws[64][LDK];

    int t = threadIdx.x;
    int row0 = blockIdx.x * 64;
    int wave = t >> 6, lane = t & 63;
    int lm = lane & 15, quad = lane >> 4;

    f32x4 acc[4];
#pragma unroll
    for (int nt = 0; nt < 4; nt++) acc[nt] = (f32x4)(0.f);

    for (int k0 = 0; k0 < IN_DIM; k0 += 64) {
        __syncthreads();
        // stage x tile: 64 rows x 64 k, f32 -> bf16
        {
            int c8 = (t & 7) * 8;            // 0..56
#pragma unroll
            for (int h = 0; h < 2; h++) {
                int r = (t >> 3) + h * 32;   // 0..63
                int gr = row0 + r;
                if (gr >= N_NODES) gr = N_NODES - 1;
                const float* xp = x + (size_t)gr * IN_DIM + k0 + c8;
                float4 v0 = *(const float4*)xp;
                float4 v1 = *(const float4*)(xp + 4);
                ushort8 pk;
                pk.s0 = f2bf(v0.x); pk.s1 = f2bf(v0.y); pk.s2 = f2bf(v0.z); pk.s3 = f2bf(v0.w);
                pk.s4 = f2bf(v1.x); pk.s5 = f2bf(v1.y); pk.s6 = f2bf(v1.z); pk.s7 = f2bf(v1.w);
                *(ushort8*)&xs[r][c8] = pk;
            }
        }
        // stage W tile from pre-transposed bf16: 64 n x 64 k
        {
            int n = t >> 2, kc = (t & 3) * 16;
            const unsigned short* wp = wt + (size_t)n * IN_DIM + k0 + kc;
            *(ushort8*)&ws[n][kc]     = *(const ushort8*)wp;
            *(ushort8*)&ws[n][kc + 8] = *(const ushort8*)(wp + 8);
        }
        __syncthreads();
#pragma unroll
        for (int kk = 0; kk < 64; kk += 32) {
            bf16x8 afrag = *(bf16x8*)&xs[wave * 16 + lm][kk + quad * 8];
#pragma unroll
            for (int nt = 0; nt < 4; nt++) {
                bf16x8 bfrag = *(bf16x8*)&ws[nt * 16 + lm][kk + quad * 8];
                acc[nt] = __builtin_amdgcn_mfma_f32_16x16x32_bf16(afrag, bfrag, acc[nt], 0, 0, 0);
            }
        }
    }
    // epilogue: C[m][n], m = quad*4 + i, n = nt*16 + lm
#pragma unroll
    for (int nt = 0; nt < 4; nt++) {
#pragma unroll
        for (int i = 0; i < 4; i++) {
            int gr = row0 + wave * 16 + quad * 4 + i;
            if (gr < N_NODES) h1[(size_t)gr * HID + nt * 16 + lm] = acc[nt][i];
        }
    }
}

// ---------- layer 1 aggregation + bias + relu (wave per node, lane = dim) ----------

__global__ __launch_bounds__(256) void k_agg1(const float* __restrict__ h1,
                                              const int* __restrict__ ptr,
                                              const int* __restrict__ csr_src,
                                              const float* __restrict__ csr_w,
                                              const float* __restrict__ dis,
                                              const float* __restrict__ b1,
                                              float* __restrict__ a1) {
    int wave = threadIdx.x >> 6, lane = threadIdx.x & 63;
    int v = blockIdx.x * 4 + wave;
    if (v >= N_NODES) return;
    float dv = dis[v];
    float acc = h1[(size_t)v * HID + lane] * dv * dv;   // self loop
    int p0 = ptr[v], p1 = ptr[v + 1];
    int p = p0;
    int n4 = p0 + ((p1 - p0) & ~3);
    for (; p < n4; p += 4) {
        int s0 = csr_src[p], s1 = csr_src[p + 1], s2 = csr_src[p + 2], s3 = csr_src[p + 3];
        float w0 = csr_w[p], w1 = csr_w[p + 1], w2 = csr_w[p + 2], w3 = csr_w[p + 3];
        float g0 = h1[(size_t)s0 * HID + lane];
        float g1 = h1[(size_t)s1 * HID + lane];
        float g2 = h1[(size_t)s2 * HID + lane];
        float g3 = h1[(size_t)s3 * HID + lane];
        acc += w0 * g0 + w1 * g1 + w2 * g2 + w3 * g3;
    }
    for (; p < p1; p++)
        acc += csr_w[p] * h1[(size_t)csr_src[p] * HID + lane];
    float r = acc + b1[lane];
    a1[(size_t)v * HID + lane] = r > 0.f ? r : 0.f;
}

// ---------- layer 2 GEMM: h2 = a1 @ W2 ----------

__global__ __launch_bounds__(256) void k_gemm2(const float* __restrict__ a1,
                                               const float* __restrict__ W2,
                                               float* __restrict__ h2) {
    __shared__ float ws[HID * NCLS];
    for (int i = threadIdx.x; i < HID * NCLS; i += 256) ws[i] = W2[i];
    __syncthreads();
    int t = blockIdx.x * 256 + threadIdx.x;
    int v = t >> 4, c = t & 15;
    if (v >= N_NODES) return;
    const float* row = a1 + (size_t)v * HID;
    float acc = 0.f;
#pragma unroll
    for (int k = 0; k < HID; k += 4) {
        float4 av = *(const float4*)(row + k);
        acc = fmaf(av.x, ws[(k + 0) * NCLS + c], acc);
        acc = fmaf(av.y, ws[(k + 1) * NCLS + c], acc);
        acc = fmaf(av.z, ws[(k + 2) * NCLS + c], acc);
        acc = fmaf(av.w, ws[(k + 3) * NCLS + c], acc);
    }
    h2[(size_t)v * NCLS + c] = acc;
}

// ---------- layer 2 aggregation + bias + log_softmax (16 lanes per node) ----------

__global__ __launch_bounds__(256) void k_agg2(const float* __restrict__ h2,
                                              const int* __restrict__ ptr,
                                              const int* __restrict__ csr_src,
                                              const float* __restrict__ csr_w,
                                              const float* __restrict__ dis,
                                              const float* __restrict__ b2,
                                              float* __restrict__ out) {
    int t = blockIdx.x * 256 + threadIdx.x;
    int v = t >> 4, c = t & 15;
    if (v >= N_NODES) return;
    float dv = dis[v];
    float acc = h2[(size_t)v * NCLS + c] * dv * dv;
    int p0 = ptr[v], p1 = ptr[v + 1];
    int p = p0;
    int n4 = p0 + ((p1 - p0) & ~3);
    for (; p < n4; p += 4) {
        int s0 = csr_src[p], s1 = csr_src[p + 1], s2 = csr_src[p + 2], s3 = csr_src[p + 3];
        float w0 = csr_w[p], w1 = csr_w[p + 1], w2 = csr_w[p + 2], w3 = csr_w[p + 3];
        float g0 = h2[(size_t)s0 * NCLS + c];
        float g1 = h2[(size_t)s1 * NCLS + c];
        float g2 = h2[(size_t)s2 * NCLS + c];
        float g3 = h2[(size_t)s3 * NCLS + c];
        acc += w0 * g0 + w1 * g1 + w2 * g2 + w3 * g3;
    }
    for (; p < p1; p++)
        acc += csr_w[p] * h2[(size_t)csr_src[p] * NCLS + c];
    acc += b2[c];
    // log-softmax over the 16-lane group
    float m = acc;
#pragma unroll
    for (int off = 8; off >= 1; off >>= 1) m = fmaxf(m, __shfl_xor(m, off, 16));
    float e = expf(acc - m);
    float s = e;
#pragma unroll
    for (int off = 8; off >= 1; off >>= 1) s += __shfl_xor(s, off, 16);
    out[(size_t)v * NCLS + c] = acc - m - logf(s);
}

// ---------- launch ----------

extern "C" void kernel_launch(void* const* d_in, const int* in_sizes, int n_in,
                              void* d_out, int out_size, void* d_ws, size_t ws_size,
                              hipStream_t stream) {
    const float* x  = (const float*)d_in[0];
    const int*   ei = (const int*)d_in[1];
    const float* w  = (const float*)d_in[2];
    const float* W1 = (const float*)d_in[3];
    const float* b1 = (const float*)d_in[4];
    const float* W2 = (const float*)d_in[5];
    const float* b2 = (const float*)d_in[6];
    const int* src = ei;               // edge_index[0]
    const int* dst = ei + N_EDGES;     // edge_index[1]

    char* wsb = (char*)d_ws;
    size_t off = 0;
    auto alloc = [&](size_t bytes) {
        void* p = wsb + off;
        off += (bytes + 255) & ~(size_t)255;
        return p;
    };
    float* deg   = (float*)alloc((size_t)N_NODES * 4);      // becomes dis after k_rsqrt
    int*   cntA  = (int*)  alloc((size_t)N_NODES * 4);
    int*   cnt2  = (int*)  alloc((size_t)N_NODES * 4);
    int*   ptr   = (int*)  alloc((size_t)(N_NODES + 1) * 4);
    int*   bsum  = (int*)  alloc((size_t)NB * 4);
    int*   csr_s = (int*)  alloc((size_t)N_EDGES * 4);
    float* csr_w = (float*)alloc((size_t)N_EDGES * 4);
    float* h1    = (float*)alloc((size_t)N_NODES * HID * 4);
    float* a1    = (float*)alloc((size_t)N_NODES * HID * 4);
    float* h2    = (float*)alloc((size_t)N_NODES * NCLS * 4);
    unsigned short* wt = (unsigned short*)alloc((size_t)HID * IN_DIM * 2);

    float* outp = (float*)d_out;

    k_init   <<<(N_NODES + 255) / 256, 256, 0, stream>>>(deg, cntA, cnt2);
    k_deg    <<<(N_EDGES + 255) / 256, 256, 0, stream>>>(src, dst, w, deg, cntA);
    k_rsqrt  <<<(N_NODES + 255) / 256, 256, 0, stream>>>(deg);
    k_scan1  <<<NB, 256, 0, stream>>>(cntA, ptr, bsum);
    k_scan2  <<<1, 128, 0, stream>>>(bsum, ptr);
    k_scan3  <<<NB, 256, 0, stream>>>(ptr, bsum);
    k_scatter<<<(N_EDGES + 255) / 256, 256, 0, stream>>>(src, dst, w, deg, ptr, cnt2, csr_s, csr_w);
    k_prep_w1<<<(HID * IN_DIM + 255) / 256, 256, 0, stream>>>(W1, wt);
    k_gemm1  <<<(N_NODES + 63) / 64, 256, 0, stream>>>(x, wt, h1);
    k_agg1   <<<(N_NODES + 3) / 4, 256, 0, stream>>>(h1, ptr, csr_s, csr_w, deg, b1, a1);
    k_gemm2  <<<(N_NODES * NCLS + 255) / 256, 256, 0, stream>>>(a1, W2, h2);
    k_agg2   <<<(N_NODES * NCLS + 255) / 256, 256, 0, stream>>>(h2, ptr, csr_s, csr_w, deg, b2, outp);
}

// Round 3
// 579.784 us; speedup vs baseline: 1.5880x; 1.1935x over previous
//
#include <hip/hip_runtime.h>
#include <hip/hip_bf16.h>

#define N_NODES 100000
#define N_EDGES 1600000
#define IN_DIM 512
#define HID 64
#define NCLS 16
#define NB ((N_NODES + 1023) / 1024)   // scan blocks (98)

typedef __attribute__((ext_vector_type(8))) short bf16x8;
typedef __attribute__((ext_vector_type(8))) unsigned short ushort8;
typedef __attribute__((ext_vector_type(4))) float f32x4;

static __device__ __forceinline__ unsigned short f2bf(float f) {
    union { float f; unsigned int u; } v; v.f = f;
    unsigned int u = v.u;
    unsigned int r = (u + 0x7fffu + ((u >> 16) & 1u)) >> 16;
    return (unsigned short)r;
}
static __device__ __forceinline__ float bf2f(unsigned short u) {
    union { unsigned int i; float f; } v; v.i = ((unsigned int)u) << 16; return v.f;
}

// ---------- graph preprocessing ----------

__global__ void k_init(int* cnt) {
    int i = blockIdx.x * 256 + threadIdx.x;
    if (i < N_NODES) cnt[i] = 0;
}

// one atomic per edge: slot within the dst row; li written coalesced
__global__ void k_pass1(const int* __restrict__ dst, int* cnt, int* __restrict__ li) {
    int e = blockIdx.x * 256 + threadIdx.x;
    if (e < N_EDGES) li[e] = atomicAdd(&cnt[dst[e]], 1);
}

// exclusive scan of cnt -> ptr, 1024 elems/block
__global__ void k_scan1(const int* __restrict__ cnt, int* ptr, int* bsum) {
    __shared__ int s[256];
    int t = threadIdx.x;
    int i0 = blockIdx.x * 1024 + t * 4;
    int c[4];
#pragma unroll
    for (int j = 0; j < 4; j++) c[j] = (i0 + j < N_NODES) ? cnt[i0 + j] : 0;
    int sum4 = c[0] + c[1] + c[2] + c[3];
    s[t] = sum4;
    __syncthreads();
    int v = sum4;
    for (int off = 1; off < 256; off <<= 1) {
        int add = (t >= off) ? s[t - off] : 0;
        __syncthreads();
        v += add;
        s[t] = v;
        __syncthreads();
    }
    int run = v - sum4;
#pragma unroll
    for (int j = 0; j < 4; j++) {
        if (i0 + j < N_NODES) ptr[i0 + j] = run;
        run += c[j];
    }
    if (t == 255) bsum[blockIdx.x] = v;
}

__global__ void k_scan2(int* bsum, int* ptr) {
    __shared__ int s[128];
    int t = threadIdx.x;
    int val = (t < NB) ? bsum[t] : 0;
    s[t] = val;
    __syncthreads();
    int v = val;
    for (int off = 1; off < 128; off <<= 1) {
        int add = (t >= off) ? s[t - off] : 0;
        __syncthreads();
        v += add;
        s[t] = v;
        __syncthreads();
    }
    if (t < NB) bsum[t] = v - val;
    if (t == 0) ptr[N_NODES] = N_EDGES;
}

__global__ void k_scan3(int* ptr, const int* __restrict__ bsum) {
    int t = threadIdx.x;
    int i0 = blockIdx.x * 1024 + t * 4;
    int add = bsum[blockIdx.x];
#pragma unroll
    for (int j = 0; j < 4; j++)
        if (i0 + j < N_NODES) ptr[i0 + j] += add;
}

// atomic-free scatter: position = ptr[dst] + li[e]
__global__ void k_pass2(const int* __restrict__ src, const int* __restrict__ dst,
                        const float* __restrict__ w, const int* __restrict__ ptr,
                        const int* __restrict__ li,
                        int* __restrict__ csr_src, float* __restrict__ csr_w) {
    int e = blockIdx.x * 256 + threadIdx.x;
    if (e < N_EDGES) {
        int p = ptr[dst[e]] + li[e];
        csr_src[p] = src[e];
        csr_w[p] = w[e];
    }
}

// deg = 1 + row-sum of raw w; dis = rsqrt(deg)
__global__ void k_degsum(const int* __restrict__ ptr, const float* __restrict__ csr_w,
                         float* __restrict__ dis) {
    int v = blockIdx.x * 256 + threadIdx.x;
    if (v < N_NODES) {
        int p0 = ptr[v], p1 = ptr[v + 1];
        float s = 1.0f;
        for (int p = p0; p < p1; p++) s += csr_w[p];
        dis[v] = rsqrtf(s);
    }
}

// csr_w[p] = w * dis[src] * dis[dst]
__global__ void k_scale(const int* __restrict__ ptr, const int* __restrict__ csr_src,
                        float* __restrict__ csr_w, const float* __restrict__ dis) {
    int v = blockIdx.x * 256 + threadIdx.x;
    if (v < N_NODES) {
        float dv = dis[v];
        int p0 = ptr[v], p1 = ptr[v + 1];
        for (int p = p0; p < p1; p++)
            csr_w[p] = csr_w[p] * dv * dis[csr_src[p]];
    }
}

// ---------- W1 transpose+cvt: wt[n][k] bf16 ----------

__global__ void k_prep_w1(const float* __restrict__ W1, unsigned short* __restrict__ wt) {
    int t = blockIdx.x * 256 + threadIdx.x;
    if (t < HID * IN_DIM) {
        int n = t >> 9, k = t & 511;
        wt[t] = f2bf(W1[(size_t)k * HID + n]);
    }
}

// ---------- layer 1 GEMM via bf16 MFMA: h1b = bf16(x @ W1) ----------

#define LDK 72

__global__ __launch_bounds__(256) void k_gemm1(const float* __restrict__ x,
                                               const unsigned short* __restrict__ wt,
                                               unsigned short* __restrict__ h1b) {
    __shared__ unsigned short xs[64][LDK];
    __shared__ unsigned short ws[64][LDK];

    int t = threadIdx.x;
    int row0 = blockIdx.x * 64;
    int wave = t >> 6, lane = t & 63;
    int lm = lane & 15, quad = lane >> 4;

    f32x4 acc[4];
#pragma unroll
    for (int nt = 0; nt < 4; nt++) acc[nt] = (f32x4)(0.f);

    for (int k0 = 0; k0 < IN_DIM; k0 += 64) {
        __syncthreads();
        {
            int c8 = (t & 7) * 8;
#pragma unroll
            for (int h = 0; h < 2; h++) {
                int r = (t >> 3) + h * 32;
                int gr = row0 + r;
                if (gr >= N_NODES) gr = N_NODES - 1;
                const float* xp = x + (size_t)gr * IN_DIM + k0 + c8;
                float4 v0 = *(const float4*)xp;
                float4 v1 = *(const float4*)(xp + 4);
                ushort8 pk;
                pk.s0 = f2bf(v0.x); pk.s1 = f2bf(v0.y); pk.s2 = f2bf(v0.z); pk.s3 = f2bf(v0.w);
                pk.s4 = f2bf(v1.x); pk.s5 = f2bf(v1.y); pk.s6 = f2bf(v1.z); pk.s7 = f2bf(v1.w);
                *(ushort8*)&xs[r][c8] = pk;
            }
        }
        {
            int n = t >> 2, kc = (t & 3) * 16;
            const unsigned short* wp = wt + (size_t)n * IN_DIM + k0 + kc;
            *(ushort8*)&ws[n][kc]     = *(const ushort8*)wp;
            *(ushort8*)&ws[n][kc + 8] = *(const ushort8*)(wp + 8);
        }
        __syncthreads();
#pragma unroll
        for (int kk = 0; kk < 64; kk += 32) {
            bf16x8 afrag = *(bf16x8*)&xs[wave * 16 + lm][kk + quad * 8];
#pragma unroll
            for (int nt = 0; nt < 4; nt++) {
                bf16x8 bfrag = *(bf16x8*)&ws[nt * 16 + lm][kk + quad * 8];
                acc[nt] = __builtin_amdgcn_mfma_f32_16x16x32_bf16(afrag, bfrag, acc[nt], 0, 0, 0);
            }
        }
    }
#pragma unroll
    for (int nt = 0; nt < 4; nt++) {
#pragma unroll
        for (int i = 0; i < 4; i++) {
            int gr = row0 + wave * 16 + quad * 4 + i;
            if (gr < N_NODES) h1b[(size_t)gr * HID + nt * 16 + lm] = f2bf(acc[nt][i]);
        }
    }
}

// ---------- layer 1 aggregation + bias + relu ----------
// wave per node: lane = (j = edge slot 0..3, c = dim chunk 0..15), 8 edges in flight

__global__ __launch_bounds__(256) void k_agg1(const unsigned short* __restrict__ h1b,
                                              const int* __restrict__ ptr,
                                              const int* __restrict__ csr_src,
                                              const float* __restrict__ csr_w,
                                              const float* __restrict__ dis,
                                              const float* __restrict__ b1,
                                              float* __restrict__ a1) {
    int wave = threadIdx.x >> 6, lane = threadIdx.x & 63;
    int v = blockIdx.x * 4 + wave;
    if (v >= N_NODES) return;
    int j = lane >> 4, c = lane & 15;
    int p0 = ptr[v], p1 = ptr[v + 1];

    float a0 = 0.f, a1r = 0.f, a2 = 0.f, a3 = 0.f;
    for (int base = p0; base < p1; base += 8) {
#pragma unroll
        for (int half = 0; half < 2; half++) {
            int idx = base + half * 4 + j;
            bool valid = idx < p1;
            int s = valid ? csr_src[idx] : v;
            float wgt = valid ? csr_w[idx] : 0.f;
            ushort4 g = *(const ushort4*)&h1b[(size_t)s * HID + c * 4];
            a0 += wgt * bf2f(g.x);
            a1r += wgt * bf2f(g.y);
            a2 += wgt * bf2f(g.z);
            a3 += wgt * bf2f(g.w);
        }
    }
    // reduce across the 4 j-groups (lane bits 4 and 5)
#pragma unroll
    for (int m = 16; m <= 32; m <<= 1) {
        a0 += __shfl_xor(a0, m, 64);
        a1r += __shfl_xor(a1r, m, 64);
        a2 += __shfl_xor(a2, m, 64);
        a3 += __shfl_xor(a3, m, 64);
    }
    if (lane < 16) {
        float dv = dis[v], dvv = dv * dv;
        ushort4 sv = *(const ushort4*)&h1b[(size_t)v * HID + c * 4];
        float4 bv = *(const float4*)&b1[c * 4];
        float r0 = a0 + dvv * bf2f(sv.x) + bv.x;
        float r1 = a1r + dvv * bf2f(sv.y) + bv.y;
        float r2 = a2 + dvv * bf2f(sv.z) + bv.z;
        float r3 = a3 + dvv * bf2f(sv.w) + bv.w;
        float4 o;
        o.x = r0 > 0.f ? r0 : 0.f;
        o.y = r1 > 0.f ? r1 : 0.f;
        o.z = r2 > 0.f ? r2 : 0.f;
        o.w = r3 > 0.f ? r3 : 0.f;
        *(float4*)&a1[(size_t)v * HID + c * 4] = o;
    }
}

// ---------- layer 2 GEMM: h2 = a1 @ W2 ----------

__global__ __launch_bounds__(256) void k_gemm2(const float* __restrict__ a1,
                                               const float* __restrict__ W2,
                                               float* __restrict__ h2) {
    __shared__ float ws[HID * NCLS];
    for (int i = threadIdx.x; i < HID * NCLS; i += 256) ws[i] = W2[i];
    __syncthreads();
    int t = blockIdx.x * 256 + threadIdx.x;
    int v = t >> 4, c = t & 15;
    if (v >= N_NODES) return;
    const float* row = a1 + (size_t)v * HID;
    float acc = 0.f;
#pragma unroll
    for (int k = 0; k < HID; k += 4) {
        float4 av = *(const float4*)(row + k);
        acc = fmaf(av.x, ws[(k + 0) * NCLS + c], acc);
        acc = fmaf(av.y, ws[(k + 1) * NCLS + c], acc);
        acc = fmaf(av.z, ws[(k + 2) * NCLS + c], acc);
        acc = fmaf(av.w, ws[(k + 3) * NCLS + c], acc);
    }
    h2[(size_t)v * NCLS + c] = acc;
}

// ---------- layer 2 aggregation + bias + log_softmax ----------

__global__ __launch_bounds__(256) void k_agg2(const float* __restrict__ h2,
                                              const int* __restrict__ ptr,
                                              const int* __restrict__ csr_src,
                                              const float* __restrict__ csr_w,
                                              const float* __restrict__ dis,
                                              const float* __restrict__ b2,
                                              float* __restrict__ out) {
    int t = blockIdx.x * 256 + threadIdx.x;
    int v = t >> 4, c = t & 15;
    if (v >= N_NODES) return;
    float dv = dis[v];
    float acc = h2[(size_t)v * NCLS + c] * dv * dv;
    int p0 = ptr[v], p1 = ptr[v + 1];
    int p = p0;
    int n4 = p0 + ((p1 - p0) & ~3);
    for (; p < n4; p += 4) {
        int s0 = csr_src[p], s1 = csr_src[p + 1], s2 = csr_src[p + 2], s3 = csr_src[p + 3];
        float w0 = csr_w[p], w1 = csr_w[p + 1], w2 = csr_w[p + 2], w3 = csr_w[p + 3];
        float g0 = h2[(size_t)s0 * NCLS + c];
        float g1 = h2[(size_t)s1 * NCLS + c];
        float g2 = h2[(size_t)s2 * NCLS + c];
        float g3 = h2[(size_t)s3 * NCLS + c];
        acc += w0 * g0 + w1 * g1 + w2 * g2 + w3 * g3;
    }
    for (; p < p1; p++)
        acc += csr_w[p] * h2[(size_t)csr_src[p] * NCLS + c];
    acc += b2[c];
    float m = acc;
#pragma unroll
    for (int off = 8; off >= 1; off >>= 1) m = fmaxf(m, __shfl_xor(m, off, 16));
    float e = expf(acc - m);
    float s = e;
#pragma unroll
    for (int off = 8; off >= 1; off >>= 1) s += __shfl_xor(s, off, 16);
    out[(size_t)v * NCLS + c] = acc - m - logf(s);
}

// ---------- launch ----------

extern "C" void kernel_launch(void* const* d_in, const int* in_sizes, int n_in,
                              void* d_out, int out_size, void* d_ws, size_t ws_size,
                              hipStream_t stream) {
    const float* x  = (const float*)d_in[0];
    const int*   ei = (const int*)d_in[1];
    const float* w  = (const float*)d_in[2];
    const float* W1 = (const float*)d_in[3];
    const float* b1 = (const float*)d_in[4];
    const float* W2 = (const float*)d_in[5];
    const float* b2 = (const float*)d_in[6];
    const int* src = ei;               // edge_index[0]
    const int* dst = ei + N_EDGES;     // edge_index[1]

    char* wsb = (char*)d_ws;
    size_t off = 0;
    auto alloc = [&](size_t bytes) {
        void* p = wsb + off;
        off += (bytes + 255) & ~(size_t)255;
        return p;
    };
    int*   cnt   = (int*)  alloc((size_t)N_NODES * 4);
    int*   li    = (int*)  alloc((size_t)N_EDGES * 4);
    int*   ptr   = (int*)  alloc((size_t)(N_NODES + 1) * 4);
    int*   bsum  = (int*)  alloc((size_t)NB * 4);
    int*   csr_s = (int*)  alloc((size_t)N_EDGES * 4);
    float* csr_w = (float*)alloc((size_t)N_EDGES * 4);
    float* dis   = (float*)alloc((size_t)N_NODES * 4);
    unsigned short* h1b = (unsigned short*)alloc((size_t)N_NODES * HID * 2);
    float* a1    = (float*)alloc((size_t)N_NODES * HID * 4);
    float* h2    = (float*)alloc((size_t)N_NODES * NCLS * 4);
    unsigned short* wt = (unsigned short*)alloc((size_t)HID * IN_DIM * 2);

    float* outp = (float*)d_out;

    k_init   <<<(N_NODES + 255) / 256, 256, 0, stream>>>(cnt);
    k_pass1  <<<(N_EDGES + 255) / 256, 256, 0, stream>>>(dst, cnt, li);
    k_scan1  <<<NB, 256, 0, stream>>>(cnt, ptr, bsum);
    k_scan2  <<<1, 128, 0, stream>>>(bsum, ptr);
    k_scan3  <<<NB, 256, 0, stream>>>(ptr, bsum);
    k_pass2  <<<(N_EDGES + 255) / 256, 256, 0, stream>>>(src, dst, w, ptr, li, csr_s, csr_w);
    k_degsum <<<(N_NODES + 255) / 256, 256, 0, stream>>>(ptr, csr_w, dis);
    k_scale  <<<(N_NODES + 255) / 256, 256, 0, stream>>>(ptr, csr_s, csr_w, dis);
    k_prep_w1<<<(HID * IN_DIM + 255) / 256, 256, 0, stream>>>(W1, wt);
    k_gemm1  <<<(N_NODES + 63) / 64, 256, 0, stream>>>(x, wt, h1b);
    k_agg1   <<<(N_NODES + 3) / 4, 256, 0, stream>>>(h1b, ptr, csr_s, csr_w, dis, b1, a1);
    k_gemm2  <<<(N_NODES * NCLS + 255) / 256, 256, 0, stream>>>(a1, W2, h2);
    k_agg2   <<<(N_NODES * NCLS + 255) / 256, 256, 0, stream>>>(h2, ptr, csr_s, csr_w, dis, b2, outp);
}